// Round 4
// baseline (2077.684 us; speedup 1.0000x reference)
//
#include <hip/hip_runtime.h>
#include <hip/hip_bf16.h>

#define BB 256
#define TT 512
#define DD 256
#define HH 512
#define G4H 2048
#define KTOT 768

typedef unsigned short u16;
typedef unsigned int u32;
typedef __attribute__((ext_vector_type(8))) short bf16x8;
typedef __attribute__((ext_vector_type(16))) float f32x16;

__device__ __forceinline__ u16 f2bf(float f) {
  union { float f; unsigned u; } v; v.f = f;
  unsigned r = v.u + 0x7FFFu + ((v.u >> 16) & 1u);
  return (u16)(r >> 16);
}
__device__ __forceinline__ float bf2f(u16 b) {
  union { unsigned u; float f; } v; v.u = ((unsigned)b) << 16;
  return v.f;
}
__device__ __forceinline__ float fsigmoid(float x) { return 1.f / (1.f + __expf(-x)); }
__device__ __forceinline__ float ftanh(float x) { return 1.f - 2.f / (__expf(2.f * x) + 1.f); }

__device__ __forceinline__ bf16x8 ld16_sc(const u16* p) {
  bf16x8 r;
  asm volatile("global_load_dwordx4 %0, %1, off sc0 sc1" : "=v"(r) : "v"(p) : "memory");
  return r;
}
__device__ __forceinline__ void st4_sc(u16* p, u32 v) {
  asm volatile("global_store_dword %0, %1, off sc0 sc1" :: "v"(p), "v"(v) : "memory");
}
__device__ __forceinline__ void waitv0() {
  asm volatile("s_waitcnt vmcnt(0)" ::: "memory");
}

// Wc rows permuted per hidden-slice: row = sl*64 + nb*32 + col', where
// (nb, col') -> gate q = nb*2 + (col'>>4), unit u = col'&15.
// So n-block 0 = [i0..15 | f0..15], n-block 1 = [g0..15 | o0..15].
__global__ __launch_bounds__(256) void lstm_init(
    const float* __restrict__ W_ih, const float* __restrict__ W_hh,
    const float* __restrict__ b_ih, const float* __restrict__ b_hh,
    u16* __restrict__ Wc, float* __restrict__ bsum,
    u16* __restrict__ h0, u32* __restrict__ flags)
{
  int idx = blockIdx.x * 256 + threadIdx.x;
  if (idx < G4H * KTOT) {
    int r = idx / KTOT, k = idx - r * KTOT;
    int slp = r >> 6, rem = r & 63;
    int q = ((rem >> 5) << 1) | ((rem >> 4) & 1);
    int u = rem & 15;
    int srow = q * HH + slp * 16 + u;
    float v = (k < HH) ? W_hh[srow * HH + k] : W_ih[srow * DD + (k - HH)];
    Wc[idx] = f2bf(v);
  }
  if (idx < G4H) bsum[idx] = b_ih[idx] + b_hh[idx];
  if (idx < BB * HH) h0[idx] = (u16)0;
  if (idx < 256) flags[idx] = 0u;
}

// x [b][t][d] f32 -> xbf2 [t][b][d] bf16 (t-major: per-step slab contiguous 128KB)
__global__ __launch_bounds__(256) void xconv(const float* __restrict__ x, u16* __restrict__ xbf2)
{
  size_t g = (size_t)blockIdx.x * 256 + threadIdx.x;
  int d8 = (int)(g & 31);
  int b  = (int)((g >> 5) & 255);
  int t  = (int)(g >> 13);
  const float* src = x + ((size_t)b * TT + t) * DD + d8 * 8;
  float4 a = *(const float4*)(src);
  float4 c = *(const float4*)(src + 4);
  bf16x8 v;
  v[0] = (short)f2bf(a.x); v[1] = (short)f2bf(a.y);
  v[2] = (short)f2bf(a.z); v[3] = (short)f2bf(a.w);
  v[4] = (short)f2bf(c.x); v[5] = (short)f2bf(c.y);
  v[6] = (short)f2bf(c.z); v[7] = (short)f2bf(c.w);
  *(bf16x8*)(xbf2 + ((size_t)t * BB + b) * DD + d8 * 8) = v;
}

// Persistent recurrence. 256 WGs (1/CU via LDS>80KB), WG=(bg of 32 batches)x(sl of 16 units).
// Wave wv: n-block nb=wv&1 (32 gate rows), K-half kh=wv>>1. W frags live in VGPRs.
// A_lds: fragment-linear, 48 kc-blocks of 1KB, slot = lane ^ ((kc&15)<<2)  -> conflict-free.
// kc 0..31 = h (k 0..511), kc 32..47 = x (k 512..767).
// kh0 owns kc {0..15, 32..39}; kh1 owns kc {16..31, 40..47}.
__global__ __launch_bounds__(256, 1) void lstm_persist(
    const u16* __restrict__ xbf2, const u16* __restrict__ Wc,
    const float* __restrict__ bsum, u16* __restrict__ h_buf,
    u32* flags)
{
  __shared__ __align__(16) unsigned char Alds[49152];   // 48 x 1024B
  __shared__ float g4[2][2][32][66];                    // 33,792B -> total 82,944B (>80KB: 1 WG/CU)

  const int tid  = threadIdx.x;
  const int bg   = blockIdx.x & 7;    // XCD-affine batch group
  const int sl   = blockIdx.x >> 3;   // hidden slice
  const int lane = tid & 63;
  const int wv   = tid >> 6;
  const int nb   = wv & 1;            // n-block (0: i|f, 1: g|o)
  const int kh   = wv >> 1;           // K-half
  const int l31  = lane & 31;
  const int lhi  = lane >> 5;

  // ---- W fragments -> VGPRs (resident all 512 steps). B-frag: n=lane&31, k=kc*16+(lane>>5)*8+j
  bf16x8 wh[16], wx[8];
  {
    const u16* wb = Wc + (size_t)(sl * 64 + nb * 32 + l31) * KTOT + lhi * 8;
    #pragma unroll
    for (int i = 0; i < 16; ++i) wh[i] = *(const bf16x8*)(wb + kh * 256 + i * 16);
    #pragma unroll
    for (int i = 0; i < 8; ++i)  wx[i] = *(const bf16x8*)(wb + 512 + kh * 128 + i * 16);
  }

  // ---- pointwise constants; cell state in registers
  const int pb2 = tid >> 3;             // batch row 0..31
  const int pu2 = (tid & 7) * 2;        // unit pair
  const int hu2 = sl * 16 + pu2;
  const int gb2 = bg * 32 + pb2;
  const float bi0 = bsum[hu2],          bi1 = bsum[hu2 + 1];
  const float bf0 = bsum[HH + hu2],     bf1 = bsum[HH + hu2 + 1];
  const float bg0 = bsum[2 * HH + hu2], bg1 = bsum[2 * HH + hu2 + 1];
  const float bo0 = bsum[3 * HH + hu2], bo1 = bsum[3 * HH + hu2 + 1];
  float c0 = 0.f, c1 = 0.f;
  u32* myflags = flags + bg * 32;

  for (int t = 0; t < TT; ++t) {
    const u16* __restrict__ h_in  = h_buf + (t & 1) * (BB * HH);
    u16* __restrict__ h_out = h_buf + ((t + 1) & 1) * (BB * HH);

    // ---- stage x slab -> Alds kc 32..47 (wave writes whole kc-blocks: conflict-free)
    #pragma unroll
    for (int j = 0; j < 4; ++j) {
      int idx = j * 256 + tid;
      int row = idx & 31, d8 = idx >> 5;
      bf16x8 v = *(const bf16x8*)(xbf2 + ((size_t)t * BB + bg * 32 + row) * DD + d8 * 8);
      int kc = 32 + (d8 >> 1);
      int slot = (((d8 & 1) << 5) | row) ^ ((kc & 15) << 2);
      *(bf16x8*)(Alds + kc * 1024 + slot * 16) = v;
    }
    // ---- wait for step t-1 producers (relaxed sc1 poll, busy)
    if (t > 0 && wv == 0 && lane < 32) {
      while (__hip_atomic_load(&myflags[lane], __ATOMIC_RELAXED, __HIP_MEMORY_SCOPE_AGENT) < (u32)t) {}
    }
    __syncthreads();   // B1

    // ---- issue coherent h loads; x-part MFMA hides the LLC latency
    bf16x8 hv[8];
    #pragma unroll
    for (int j = 0; j < 8; ++j) {
      int idx = j * 256 + tid;
      int row = idx & 31, col8 = idx >> 5;
      hv[j] = ld16_sc(h_in + (size_t)(bg * 32 + row) * HH + col8 * 8);
    }
    f32x16 accA = {0,0,0,0,0,0,0,0,0,0,0,0,0,0,0,0};
    f32x16 accB = {0,0,0,0,0,0,0,0,0,0,0,0,0,0,0,0};
    #pragma unroll
    for (int i = 0; i < 8; ++i) {
      int kc = 32 + kh * 8 + i;
      bf16x8 a = *(const bf16x8*)(Alds + kc * 1024 + (size_t)((lane ^ ((kc & 15) << 2)) * 16));
      if (i & 1) accB = __builtin_amdgcn_mfma_f32_32x32x16_bf16(a, wx[i], accB, 0, 0, 0);
      else       accA = __builtin_amdgcn_mfma_f32_32x32x16_bf16(a, wx[i], accA, 0, 0, 0);
    }
    waitv0();                              // h in regs
    __builtin_amdgcn_sched_barrier(0);
    #pragma unroll
    for (int j = 0; j < 8; ++j) {
      int idx = j * 256 + tid;
      int row = idx & 31, col8 = idx >> 5;
      int kc = col8 >> 1;
      int slot = (((col8 & 1) << 5) | row) ^ ((kc & 15) << 2);
      *(bf16x8*)(Alds + kc * 1024 + slot * 16) = hv[j];
    }
    __syncthreads();   // B2

    // ---- h-part MFMA (16 kc per wave)
    #pragma unroll
    for (int i = 0; i < 16; ++i) {
      int kc = kh * 16 + i;
      bf16x8 a = *(const bf16x8*)(Alds + kc * 1024 + (size_t)((lane ^ ((kc & 15) << 2)) * 16));
      if (i & 1) accB = __builtin_amdgcn_mfma_f32_32x32x16_bf16(a, wh[i], accB, 0, 0, 0);
      else       accA = __builtin_amdgcn_mfma_f32_32x32x16_bf16(a, wh[i], accA, 0, 0, 0);
    }
    // C/D layout (m74/m101): col = lane&31, row = (reg&3) + 8*(reg>>2) + 4*(lane>>5)
    #pragma unroll
    for (int r = 0; r < 16; ++r) {
      int grow = (r & 3) + 8 * (r >> 2) + 4 * lhi;
      g4[kh][nb][grow][l31] = accA[r] + accB[r];
    }
    __syncthreads();   // B3

    // ---- pointwise: sum K-halves, cell update, packed coherent h store
    {
      float gi0 = g4[0][0][pb2][pu2]      + g4[1][0][pb2][pu2]      + bi0;
      float gf_0 = g4[0][0][pb2][16 + pu2] + g4[1][0][pb2][16 + pu2] + bf0;
      float gg0 = g4[0][1][pb2][pu2]      + g4[1][1][pb2][pu2]      + bg0;
      float go0 = g4[0][1][pb2][16 + pu2] + g4[1][1][pb2][16 + pu2] + bo0;
      float gi1 = g4[0][0][pb2][pu2 + 1]      + g4[1][0][pb2][pu2 + 1]      + bi1;
      float gf_1 = g4[0][0][pb2][17 + pu2] + g4[1][0][pb2][17 + pu2] + bf1;
      float gg1 = g4[0][1][pb2][pu2 + 1]      + g4[1][1][pb2][pu2 + 1]      + bg1;
      float go1 = g4[0][1][pb2][17 + pu2] + g4[1][1][pb2][17 + pu2] + bo1;
      c0 = fsigmoid(gf_0) * c0 + fsigmoid(gi0) * ftanh(gg0);
      c1 = fsigmoid(gf_1) * c1 + fsigmoid(gi1) * ftanh(gg1);
      u32 ha = (u32)f2bf(fsigmoid(go0) * ftanh(c0));
      u32 hb = (u32)f2bf(fsigmoid(go1) * ftanh(c1));
      st4_sc(h_out + (size_t)gb2 * HH + hu2, ha | (hb << 16));
    }
    waitv0();          // own h stores at coherent point
    __syncthreads();   // B4
    if (tid == 0)
      __hip_atomic_store(&myflags[sl], (u32)(t + 1), __ATOMIC_RELAXED, __HIP_MEMORY_SCOPE_AGENT);
  }
}

__global__ __launch_bounds__(256) void lstm_final(
    const u16* __restrict__ h, const float* __restrict__ fc_w,
    const float* __restrict__ fc_b, float* __restrict__ out)
{
  int b = threadIdx.x;
  float s = 0.f;
  const u16* hp = h + (size_t)b * HH;
  #pragma unroll 8
  for (int k = 0; k < HH; k += 8) {
    bf16x8 v = *(const bf16x8*)(hp + k);
    #pragma unroll
    for (int j = 0; j < 8; ++j) s += bf2f((u16)v[j]) * fc_w[k + j];
  }
  s += fc_b[0];
  out[b] = fsigmoid(s);
}

extern "C" void kernel_launch(void* const* d_in, const int* in_sizes, int n_in,
                              void* d_out, int out_size, void* d_ws, size_t ws_size,
                              hipStream_t stream) {
  (void)in_sizes; (void)n_in; (void)out_size; (void)ws_size;
  const float* x    = (const float*)d_in[0];
  const float* W_ih = (const float*)d_in[1];
  const float* W_hh = (const float*)d_in[2];
  const float* b_ih = (const float*)d_in[3];
  const float* b_hh = (const float*)d_in[4];
  const float* fc_w = (const float*)d_in[5];
  const float* fc_b = (const float*)d_in[6];
  float* out = (float*)d_out;

  char* ws = (char*)d_ws;
  u16*   Wc    = (u16*)(ws);                 // 3,145,728 B (permuted rows)
  float* bsum  = (float*)(ws + 3145728);     //     8,192 B
  u16*   h_buf = (u16*)(ws + 3153920);       //   524,288 B (double-buffered h)
  u32*   flags = (u32*)(ws + 3678208);       //     1,024 B
  u16*   xbf2  = (u16*)(ws + 4194304);       // 67,108,864 B (x bf16, t-major)

  lstm_init<<<6144, 256, 0, stream>>>(W_ih, W_hh, b_ih, b_hh, Wc, bsum, h_buf, flags);
  xconv<<<16384, 256, 0, stream>>>(x, xbf2);
  void* args[] = { (void*)&xbf2, (void*)&Wc, (void*)&bsum, (void*)&h_buf, (void*)&flags };
  (void)hipLaunchCooperativeKernel((void*)lstm_persist, dim3(256), dim3(256), args, 0, stream);
  lstm_final<<<1, 256, 0, stream>>>(h_buf, fc_w, fc_b, out);
}